// Round 4
// baseline (207.160 us; speedup 1.0000x reference)
//
#include <hip/hip_runtime.h>
#include <hip/hip_bf16.h>
#include <math.h>

#define N_NODES 10000
#define D_MODEL 128
#define E_EDGES 320000
#define P_EDGES 80000
#define LN_EPS 1e-5f
#define CAP 32             // slots per bucket (Poisson(8): P(>32) ~ 1e-11)
#define M_ROWS 50000       // = 625 blocks * 80 rows, exact
#define NCOLS 160          // delta(128) + B(16) + C(16)

typedef __attribute__((ext_vector_type(8))) short bf16x8;
typedef __attribute__((ext_vector_type(4))) float f32x4;

__device__ __forceinline__ unsigned short f2bf(float f) {
    __hip_bfloat16 h = __float2bfloat16(f);
    return *reinterpret_cast<unsigned short*>(&h);
}
__device__ __forceinline__ float bf2f(unsigned int u) {
    return __uint_as_float(u << 16);
}

// ---------------------------------------------------------------------------
// prep_all: pack Wcat(160) + W_out + W_g (B-frag layout), x/rel -> bf16
// (x also into s=0 token rows), zero counters, pack edge triples.
// ---------------------------------------------------------------------------
__global__ __launch_bounds__(256) void prep_all(
    const float* __restrict__ Wd, const float* __restrict__ Wb,
    const float* __restrict__ Wc, const float* __restrict__ Wg,
    const float* __restrict__ W_out,
    const float* __restrict__ x, const float* __restrict__ rel,
    const int* __restrict__ edge_index, const int* __restrict__ edge_type,
    unsigned short* __restrict__ Bp, unsigned short* __restrict__ Wop,
    unsigned short* __restrict__ Wgp,
    unsigned short* __restrict__ x_bf, unsigned short* __restrict__ rel_bf,
    int* __restrict__ cnt, int4* __restrict__ ed4,
    unsigned short* __restrict__ tokens)
{
    int gid = blockIdx.x * 256 + threadIdx.x;
    if (gid < 20480) {                         // Bp: 128 x 160
        int k = gid / NCOLS, n = gid - (gid / NCOLS) * NCOLS;
        float v;
        if (n < 128)      v = Wd[k * 128 + n];
        else if (n < 144) v = Wb[k * 16 + (n - 128)];
        else              v = Wc[k * 16 + (n - 144)];
        Bp[((size_t)(k >> 3) * NCOLS + n) * 8 + (k & 7)] = f2bf(v);
    } else if (gid < 36864) {                  // Wop: 128 x 128
        int i = gid - 20480;
        int k = i >> 7, n = i & 127;
        Wop[((size_t)(k >> 3) * 128 + n) * 8 + (k & 7)] = f2bf(W_out[k * 128 + n]);
    } else if (gid < 53248) {                  // Wgp: 128 x 128
        int i = gid - 36864;
        int k = i >> 7, n = i & 127;
        Wgp[((size_t)(k >> 3) * 128 + n) * 8 + (k & 7)] = f2bf(Wg[k * 128 + n]);
    } else if (gid < 94208) {
        cnt[gid - 53248] = 0;
    } else if (gid < 119808) {
        int i = gid - 94208;
        rel_bf[i] = f2bf(rel[i]);
    } else if (gid < 1399808) {
        int i = gid - 119808;
        unsigned short v = f2bf(x[i]);
        x_bf[i] = v;
        tokens[(size_t)(i >> 7) * 640 + (i & 127)] = v;   // s=0 token row
    } else if (gid < 1719808) {
        int e = gid - 1399808;
        ed4[e] = make_int4(edge_index[e], edge_index[E_EDGES + e], edge_type[e], 0);
    }
}

// ---------------------------------------------------------------------------
// One-pass CSR into fixed-capacity bucket slots (1 random 16B load per edge).
// ---------------------------------------------------------------------------
__global__ __launch_bounds__(256) void csr_build(
    const int4* __restrict__ ed4, const int* __restrict__ perms,
    int* __restrict__ cnt, int2* __restrict__ slots)
{
    int gid = blockIdx.x * blockDim.x + threadIdx.x;
    if (gid >= 4 * P_EDGES) return;
    int s = gid / P_EDGES;
    int e = perms[gid];
    int4 ed = ed4[e];
    int b = ed.y * 4 + s;
    int pos = atomicAdd(&cnt[b], 1);
    if (pos < CAP) slots[(size_t)b * CAP + pos] = make_int2(ed.x, ed.z);
}

// ---------------------------------------------------------------------------
// Gather (wide: 10000 blocks): one wave per bucket; lane = 2 dims;
// 4 edges in flight.
// ---------------------------------------------------------------------------
__global__ __launch_bounds__(256) void gather_tokens(
    const unsigned short* __restrict__ x_bf,
    const int* __restrict__ cnt, const int2* __restrict__ slots,
    const unsigned short* __restrict__ rel_bf,
    unsigned short* __restrict__ tokens)
{
    int n = blockIdx.x;
    int w = threadIdx.x >> 6, lane = threadIdx.x & 63;
    int b = n * 4 + w;
    int c = cnt[b];
    int cc = c < CAP ? c : CAP;
    const int2* sl = slots + (size_t)b * CAP;
    const unsigned int* xu = (const unsigned int*)x_bf;
    const unsigned int* ru = (const unsigned int*)rel_bf;
    float ax = 0.f, ay = 0.f;
    int j = 0;
    for (; j + 4 <= cc; j += 4) {
        int4 e01 = *(const int4*)(sl + j);
        int4 e23 = *(const int4*)(sl + j + 2);
        unsigned int x0 = xu[(size_t)e01.x * 64 + lane];
        unsigned int r0 = ru[(size_t)e01.y * 64 + lane];
        unsigned int x1 = xu[(size_t)e01.z * 64 + lane];
        unsigned int r1 = ru[(size_t)e01.w * 64 + lane];
        unsigned int x2 = xu[(size_t)e23.x * 64 + lane];
        unsigned int r2 = ru[(size_t)e23.y * 64 + lane];
        unsigned int x3 = xu[(size_t)e23.z * 64 + lane];
        unsigned int r3 = ru[(size_t)e23.w * 64 + lane];
        ax += (bf2f(x0 & 0xffffu) + bf2f(r0 & 0xffffu))
            + (bf2f(x1 & 0xffffu) + bf2f(r1 & 0xffffu))
            + (bf2f(x2 & 0xffffu) + bf2f(r2 & 0xffffu))
            + (bf2f(x3 & 0xffffu) + bf2f(r3 & 0xffffu));
        ay += (bf2f(x0 >> 16) + bf2f(r0 >> 16))
            + (bf2f(x1 >> 16) + bf2f(r1 >> 16))
            + (bf2f(x2 >> 16) + bf2f(r2 >> 16))
            + (bf2f(x3 >> 16) + bf2f(r3 >> 16));
    }
    if (j + 2 <= cc) {
        int4 e01 = *(const int4*)(sl + j);
        unsigned int x0 = xu[(size_t)e01.x * 64 + lane];
        unsigned int r0 = ru[(size_t)e01.y * 64 + lane];
        unsigned int x1 = xu[(size_t)e01.z * 64 + lane];
        unsigned int r1 = ru[(size_t)e01.w * 64 + lane];
        ax += (bf2f(x0 & 0xffffu) + bf2f(r0 & 0xffffu))
            + (bf2f(x1 & 0xffffu) + bf2f(r1 & 0xffffu));
        ay += (bf2f(x0 >> 16) + bf2f(r0 >> 16))
            + (bf2f(x1 >> 16) + bf2f(r1 >> 16));
        j += 2;
    }
    if (j < cc) {
        int2 se = sl[j];
        unsigned int xa = xu[(size_t)se.x * 64 + lane];
        unsigned int ra = ru[(size_t)se.y * 64 + lane];
        ax += bf2f(xa & 0xffffu) + bf2f(ra & 0xffffu);
        ay += bf2f(xa >> 16) + bf2f(ra >> 16);
    }
    float inv = 1.f / fmaxf((float)c, 1.f);
    unsigned int pack = (unsigned int)f2bf(ax * inv)
                      | ((unsigned int)f2bf(ay * inv) << 16);
    ((unsigned int*)tokens)[((size_t)n * 5 + w + 1) * 64 + lane] = pack;
}

// ---------------------------------------------------------------------------
// MEGA: gemm1 + scan + out fused per 16-node block (80 token rows).
// delta/bc/so live entirely in LDS -> zero intermediate HBM traffic.
// 625 blocks x 256 threads.
// ---------------------------------------------------------------------------
__global__ __launch_bounds__(256) void mega(
    const unsigned short* __restrict__ tokens,
    const unsigned short* __restrict__ Bp,
    const unsigned short* __restrict__ Wop,
    const unsigned short* __restrict__ Wgp,
    const unsigned short* __restrict__ x_bf,
    const float* __restrict__ x,
    const float* __restrict__ log_A,
    const float* __restrict__ b_delta, const float* __restrict__ b_g,
    const float* __restrict__ b_out,
    const float* __restrict__ ln_g, const float* __restrict__ ln_b,
    float* __restrict__ out)
{
    const int tid = threadIdx.x;
    const int wv = tid >> 6, lane = tid & 63;
    const int quad = lane >> 4, l16 = lane & 15;
    const int m0 = blockIdx.x * 80;       // global token-row base
    const int n0 = blockIdx.x * 16;       // global node base

    // LDS: phase1 {delta 20480 | bcf 10240 | so 4096}, out-phase aliases
    // res/pmu/pv2/mu into the (then-dead) delta/bcf regions.
    __shared__ __align__(16) char smem[34816];
    unsigned short* s_delta = (unsigned short*)smem;            // [80][128] bf16
    float*          s_bcf   = (float*)(smem + 20480);           // [80][32] f32
    unsigned short* s_so    = (unsigned short*)(smem + 30720);  // [16][128] bf16 (swz)
    float* s_res  = (float*)smem;                               // [16][132] f32
    float* s_pmu  = (float*)(smem + 20480);                     // [16][16]
    float* s_pv2  = (float*)(smem + 21504);                     // [16][16]
    float* s_mu   = (float*)(smem + 22528);                     // [16]
    float* s_rstd = (float*)(smem + 22592);                     // [16]

    // ---------------- phase 1: GEMM1  Z[80,160] -> s_delta | s_bcf
    // 50 units = 5 row-frags x 10 col-tiles, round-robin over 4 waves.
    for (int u = wv; u < 50; u += 4) {
        int f = u / 10, t = u - (u / 10) * 10;
        f32x4 acc = {0.f, 0.f, 0.f, 0.f};
        const unsigned short* arow =
            tokens + (size_t)(m0 + f * 16 + l16) * 128 + quad * 8;
        #pragma unroll
        for (int kc = 0; kc < 128; kc += 32) {
            bf16x8 a = *(const bf16x8*)(arow + kc);
            bf16x8 b = *(const bf16x8*)(Bp +
                ((size_t)(kc / 8 + quad) * NCOLS + 16 * t + l16) * 8);
            acc = __builtin_amdgcn_mfma_f32_16x16x32_bf16(a, b, acc, 0, 0, 0);
        }
        int rbase = f * 16 + quad * 4;
        int c = 16 * t + l16;
        #pragma unroll
        for (int reg = 0; reg < 4; ++reg) {
            int r = rbase + reg;              // local row 0..79 (= node*5+s)
            float v = acc[reg];
            if (t < 8) {
                float z = v + b_delta[c];
                float d = (z > 15.f) ? z : log1pf(__expf(z));
                s_delta[r * 128 + c] = f2bf(d);
            } else {
                s_bcf[r * 32 + (c - 128)] = v;   // f32 (B:0-15 | C:16-31)
            }
        }
    }
    __syncthreads();

    // ---------------- phase 2: bidirectional selective scan -> s_so
    // 2048 (node,dim) units / 256 threads = 8 each; thread owns one dim.
    {
        const int dim = tid & 127;
        float Ac[16];
        {
            const float4* la = (const float4*)(log_A + dim * 16);
            #pragma unroll
            for (int q = 0; q < 4; ++q) {
                float4 lv = la[q];
                Ac[q * 4 + 0] = -__expf(lv.x);
                Ac[q * 4 + 1] = -__expf(lv.y);
                Ac[q * 4 + 2] = -__expf(lv.z);
                Ac[q * 4 + 3] = -__expf(lv.w);
            }
        }
        #pragma unroll
        for (int i = 0; i < 8; ++i) {
            int node = (tid >> 7) + 2 * i;    // local node 0..15
            const float* bcn = s_bcf + node * 160;       // [5][32]
            float tv[5], dl[5];
            {
                const unsigned short* tb =
                    tokens + ((size_t)(n0 + node) * 5) * 128 + dim;
                const unsigned short* db = s_delta + node * 640 + dim;
                #pragma unroll
                for (int s = 0; s < 5; ++s) {
                    tv[s] = bf2f(tb[s * 128]);
                    dl[s] = bf2f(db[s * 128]);
                }
            }
            float st[16], V[16];
            #pragma unroll
            for (int k = 0; k < 16; ++k) { st[k] = 0.f; V[k] = bcn[16 + k]; }
            float total = 0.f;
            #pragma unroll
            for (int s = 0; s < 5; ++s) {
                float dtv = dl[s] * tv[s];
                float yf = 0.f, ub = 0.f;
                #pragma unroll
                for (int k = 0; k < 16; ++k) {
                    float B = bcn[s * 32 + k];
                    float C = bcn[s * 32 + 16 + k];
                    float A = __expf(dl[s] * Ac[k]);
                    st[k] = fmaf(A, st[k], dtv * B);
                    yf = fmaf(st[k], C, yf);
                    ub = fmaf(V[k], B, ub);              // V_s (pre-update)
                    if (s < 4) V[k] = fmaf(A, V[k], bcn[(s + 1) * 32 + 16 + k]);
                }
                total += yf + dtv * ub;
            }
            // swizzled store: chunk(16B) ^= node&7 -> conflict-free b128 reads
            s_so[node * 128 + (((dim >> 3) ^ (node & 7)) << 3) + (dim & 7)] =
                f2bf(total * 0.2f);
        }
    }
    __syncthreads();

    // ---------------- phase 3: out = LN(x + silu(x@Wg+bg)*(so@Wo+bo))
    {
        f32x4 accO[2] = {{0,0,0,0},{0,0,0,0}};
        f32x4 accG[2] = {{0,0,0,0},{0,0,0,0}};
        const unsigned short* grow = x_bf + (size_t)(n0 + l16) * 128 + quad * 8;
        #pragma unroll
        for (int kc = 0; kc < 128; kc += 32) {
            // so A-frag from LDS with matching swizzle (row=l16, chunk=kc/8+quad)
            bf16x8 a = *(const bf16x8*)(s_so + l16 * 128 +
                           (((kc / 8 + quad) ^ (l16 & 7)) << 3));
            bf16x8 ag = *(const bf16x8*)(grow + kc);
            #pragma unroll
            for (int tt = 0; tt < 2; ++tt) {
                int t = wv * 2 + tt;
                size_t bi = ((size_t)(kc / 8 + quad) * 128 + 16 * t + l16) * 8;
                bf16x8 bo = *(const bf16x8*)(Wop + bi);
                bf16x8 bg = *(const bf16x8*)(Wgp + bi);
                accO[tt] = __builtin_amdgcn_mfma_f32_16x16x32_bf16(a,  bo, accO[tt], 0, 0, 0);
                accG[tt] = __builtin_amdgcn_mfma_f32_16x16x32_bf16(ag, bg, accG[tt], 0, 0, 0);
            }
        }

        #pragma unroll
        for (int tt = 0; tt < 2; ++tt) {
            int c = wv * 32 + tt * 16 + l16;
            #pragma unroll
            for (int reg = 0; reg < 4; ++reg) {
                int lrow = quad * 4 + reg;
                float o  = accO[tt][reg] + b_out[c];
                float gl = accG[tt][reg] + b_g[c];
                float gate = gl / (1.f + __expf(-gl));
                s_res[lrow * 132 + c] = x[(size_t)(n0 + lrow) * 128 + c] + gate * o;
            }
        }
        __syncthreads();

        {
            int row = tid >> 4, q = tid & 15;
            float s = 0.f, s2 = 0.f;
            #pragma unroll
            for (int i = 0; i < 8; ++i) {
                float vv = s_res[row * 132 + q + 16 * i];
                s += vv; s2 += vv * vv;
            }
            s_pmu[row * 16 + q] = s; s_pv2[row * 16 + q] = s2;
        }
        __syncthreads();
        if (tid < 16) {
            float s = 0.f, s2 = 0.f;
            #pragma unroll
            for (int i = 0; i < 16; ++i) { s += s_pmu[tid * 16 + i]; s2 += s_pv2[tid * 16 + i]; }
            float mu = s * (1.f / 128.f);
            float var = s2 * (1.f / 128.f) - mu * mu;
            s_mu[tid] = mu;
            s_rstd[tid] = rsqrtf(var + LN_EPS);
        }
        __syncthreads();
        #pragma unroll
        for (int i = 0; i < 8; ++i) {
            int idx = i * 256 + tid;
            int row = idx >> 7, c = idx & 127;
            out[(size_t)(n0 + row) * 128 + c] =
                (s_res[row * 132 + c] - s_mu[row]) * s_rstd[row] * ln_g[c] + ln_b[c];
        }
    }
}

// ---------------------------------------------------------------------------
extern "C" void kernel_launch(void* const* d_in, const int* in_sizes, int n_in,
                              void* d_out, int out_size, void* d_ws, size_t ws_size,
                              hipStream_t stream) {
    const float* x          = (const float*)d_in[0];
    const int*   edge_index = (const int*)  d_in[1];
    const int*   edge_type  = (const int*)  d_in[2];
    const int*   perms      = (const int*)  d_in[3];
    const float* rel_table  = (const float*)d_in[4];
    const float* log_A      = (const float*)d_in[5];
    const float* W_B        = (const float*)d_in[6];
    const float* W_C        = (const float*)d_in[7];
    const float* W_delta    = (const float*)d_in[8];
    const float* b_delta    = (const float*)d_in[9];
    const float* W_g        = (const float*)d_in[10];
    const float* b_g        = (const float*)d_in[11];
    const float* W_out      = (const float*)d_in[12];
    const float* b_out      = (const float*)d_in[13];
    const float* ln_g       = (const float*)d_in[14];
    const float* ln_b       = (const float*)d_in[15];

    char* ws = (char*)d_ws;
    int*            cnt    = (int*)           (ws + 0);          //   163840
    unsigned short* Bp     = (unsigned short*)(ws + 163840);     //    40960
    unsigned short* Wop    = (unsigned short*)(ws + 204800);     //    32768
    unsigned short* Wgp    = (unsigned short*)(ws + 237568);     //    32768
    unsigned short* x_bf   = (unsigned short*)(ws + 270336);     //  2560000
    unsigned short* rel_bf = (unsigned short*)(ws + 2830336);    //    51200
    int4*           ed4    = (int4*)          (ws + 2881536);    //  5120000
    unsigned short* tokens = (unsigned short*)(ws + 8001536);    // 12800000
    int2*           slots  = (int2*)          (ws + 20801536);   // 10485760

    prep_all<<<6718, 256, 0, stream>>>(
        W_delta, W_B, W_C, W_g, W_out, x, rel_table, edge_index, edge_type,
        Bp, Wop, Wgp, x_bf, rel_bf, cnt, ed4, tokens);

    csr_build<<<(4 * P_EDGES + 255) / 256, 256, 0, stream>>>(
        ed4, perms, cnt, slots);

    gather_tokens<<<N_NODES, 256, 0, stream>>>(
        x_bf, cnt, slots, rel_bf, tokens);

    mega<<<N_NODES / 16, 256, 0, stream>>>(
        tokens, Bp, Wop, Wgp, x_bf, x, log_A, b_delta, b_g, b_out,
        ln_g, ln_b, (float*)d_out);
}